// Round 1
// baseline (434.859 us; speedup 1.0000x reference)
//
#include <hip/hip_runtime.h>
#include <hip/hip_bf16.h>

#define H_DIM 1024
#define I_DIM 2048
#define NEXP  16
#define NTOK  4096
#define BM 64
#define BN 64
#define BK 32
#define LDSW 40                      // LDS row stride in shorts (80B, bank-conflict-free)
#define MAXS (NTOK*2 + NEXP*BM)      // 9216 padded slots max
#define MAXRB (MAXS/BM)              // 144 row blocks

typedef __attribute__((ext_vector_type(8))) short short8;
typedef __attribute__((ext_vector_type(4))) float f32x4;

__device__ inline short f2bf(float f) {
    union { float f; unsigned u; } v; v.f = f;
    unsigned u = v.u + 0x7FFFu + ((v.u >> 16) & 1u);   // RNE
    return (short)(u >> 16);
}

// ---------------- gate: one wave per token ----------------
__global__ __launch_bounds__(256) void gate_kernel(
    const float* __restrict__ x, const float* __restrict__ Wg,
    int* __restrict__ cnt, int* __restrict__ tokE, float* __restrict__ tokW)
{
    const int wave = (blockIdx.x * blockDim.x + threadIdx.x) >> 6;   // token id
    const int lane = threadIdx.x & 63;
    if (wave >= NTOK) return;
    const float* xr = x + (size_t)wave * H_DIM;

    float acc[NEXP];
#pragma unroll
    for (int e = 0; e < NEXP; e++) acc[e] = 0.f;
    for (int j = lane; j < H_DIM; j += 64) {
        const float xv = xr[j];
#pragma unroll
        for (int e = 0; e < NEXP; e++) acc[e] = fmaf(xv, Wg[e * H_DIM + j], acc[e]);
    }
#pragma unroll
    for (int off = 32; off; off >>= 1) {
#pragma unroll
        for (int e = 0; e < NEXP; e++) acc[e] += __shfl_xor(acc[e], off, 64);
    }
    if (lane == 0) {
        float m = acc[0];
#pragma unroll
        for (int e = 1; e < NEXP; e++) m = fmaxf(m, acc[e]);
        float p[NEXP]; float s = 0.f;
#pragma unroll
        for (int e = 0; e < NEXP; e++) { p[e] = __expf(acc[e] - m); s += p[e]; }
        int i1 = 0;
#pragma unroll
        for (int e = 1; e < NEXP; e++) if (acc[e] > acc[i1]) i1 = e;
        int i2 = -1;
#pragma unroll
        for (int e = 0; e < NEXP; e++) {
            if (e == i1) continue;
            if (i2 < 0 || acc[e] > acc[i2]) i2 = e;
        }
        const float inv = 1.f / s;
        tokE[wave*2+0] = i1; tokW[wave*2+0] = p[i1] * inv;
        tokE[wave*2+1] = i2; tokW[wave*2+1] = p[i2] * inv;
        atomicAdd(&cnt[i1], 1); atomicAdd(&cnt[i2], 1);
    }
}

// ---------------- scan: aligned prefix sum (1 thread) ----------------
__global__ void scan_kernel(const int* __restrict__ cnt, int* __restrict__ aoff)
{
    if (threadIdx.x == 0 && blockIdx.x == 0) {
        int acc = 0;
        for (int e = 0; e < NEXP; e++) {
            aoff[e] = acc;
            acc += ((cnt[e] + BM - 1) / BM) * BM;   // align expert range to BM
        }
        aoff[NEXP] = acc;
    }
}

// ---------------- scatter: fill compacted slot lists ----------------
__global__ __launch_bounds__(256) void scatter_kernel(
    const int* __restrict__ tokE, const float* __restrict__ tokW,
    const int* __restrict__ aoff, int* __restrict__ fill,
    int* __restrict__ tok_of_slot, float* __restrict__ w_of_slot)
{
    const int t = blockIdx.x * blockDim.x + threadIdx.x;
    if (t >= NTOK) return;
#pragma unroll
    for (int k = 0; k < 2; k++) {
        const int e = tokE[t*2+k];
        const int pos = atomicAdd(&fill[e], 1);
        const int slot = aoff[e] + pos;
        tok_of_slot[slot] = t;
        w_of_slot[slot] = tokW[t*2+k];
    }
}

// ---------------- fc1: h = silu(X W1^T), gathered rows, bf16 out ----------------
__global__ __launch_bounds__(256) void fc1_kernel(
    const float* __restrict__ x, const float* __restrict__ W1,
    const int* __restrict__ aoff, const int* __restrict__ tok_of_slot,
    short* __restrict__ h)
{
    const int total = aoff[NEXP];
    const int row0 = blockIdx.y * BM;
    if (row0 >= total) return;
    int e = 0;
    while (aoff[e+1] <= row0) e++;
    const float* __restrict__ W = W1 + (size_t)e * I_DIM * H_DIM;
    const int col0 = blockIdx.x * BN;

    __shared__ short As[BM * LDSW];
    __shared__ short Bs[BN * LDSW];
    __shared__ int toks[BM];

    const int tid = threadIdx.x;
    if (tid < BM) toks[tid] = tok_of_slot[row0 + tid];
    __syncthreads();

    const int wid = tid >> 6, lane = tid & 63;
    const int sr  = tid >> 2;            // staging row 0..63
    const int skc = (tid & 3) * 8;       // staging k offset (0/8/16/24)

    const float* aSrc = nullptr;
    { const int tok = toks[sr]; if (tok >= 0) aSrc = x + (size_t)tok * H_DIM; }
    const float* bSrc = W + (size_t)(col0 + sr) * H_DIM;

    const int frow = lane & 15, fk = (lane >> 4) * 8;

    f32x4 acc[4];
#pragma unroll
    for (int n = 0; n < 4; n++) acc[n] = (f32x4){0.f, 0.f, 0.f, 0.f};

    for (int k0 = 0; k0 < H_DIM; k0 += BK) {
        short8 av;
        if (aSrc) {
            const float4 f0 = *(const float4*)(aSrc + k0 + skc);
            const float4 f1 = *(const float4*)(aSrc + k0 + skc + 4);
            av = (short8){ f2bf(f0.x), f2bf(f0.y), f2bf(f0.z), f2bf(f0.w),
                           f2bf(f1.x), f2bf(f1.y), f2bf(f1.z), f2bf(f1.w) };
        } else {
            av = (short8){0,0,0,0,0,0,0,0};
        }
        const float4 g0 = *(const float4*)(bSrc + k0 + skc);
        const float4 g1 = *(const float4*)(bSrc + k0 + skc + 4);
        const short8 bv = (short8){ f2bf(g0.x), f2bf(g0.y), f2bf(g0.z), f2bf(g0.w),
                                    f2bf(g1.x), f2bf(g1.y), f2bf(g1.z), f2bf(g1.w) };
        *(short8*)(&As[sr*LDSW + skc]) = av;
        *(short8*)(&Bs[sr*LDSW + skc]) = bv;
        __syncthreads();

        const short8 af = *(short8*)(&As[(wid*16 + frow)*LDSW + fk]);
#pragma unroll
        for (int n = 0; n < 4; n++) {
            const short8 bf = *(short8*)(&Bs[(n*16 + frow)*LDSW + fk]);
            acc[n] = __builtin_amdgcn_mfma_f32_16x16x32_bf16(af, bf, acc[n], 0, 0, 0);
        }
        __syncthreads();
    }

    // epilogue: SiLU -> bf16 h.  D layout: col=lane&15, row=(lane>>4)*4+r
    const int mrow0 = row0 + wid*16 + (lane >> 4) * 4;
    const int icol0 = col0 + (lane & 15);
#pragma unroll
    for (int n = 0; n < 4; n++) {
#pragma unroll
        for (int r = 0; r < 4; r++) {
            const float v = acc[n][r];
            const float sv = v / (1.f + __expf(-v));
            h[(size_t)(mrow0 + r) * I_DIM + icol0 + n*16] = f2bf(sv);
        }
    }
}

// ---------------- fc2: y[tok] += w * (h W2^T) ----------------
__global__ __launch_bounds__(256) void fc2_kernel(
    const short* __restrict__ h, const float* __restrict__ W2,
    const int* __restrict__ aoff, const int* __restrict__ tok_of_slot,
    const float* __restrict__ w_of_slot, float* __restrict__ y)
{
    const int total = aoff[NEXP];
    const int row0 = blockIdx.y * BM;
    if (row0 >= total) return;
    int e = 0;
    while (aoff[e+1] <= row0) e++;
    const float* __restrict__ W = W2 + (size_t)e * H_DIM * I_DIM;
    const int col0 = blockIdx.x * BN;

    __shared__ short As[BM * LDSW];
    __shared__ short Bs[BN * LDSW];

    const int tid = threadIdx.x;
    const int wid = tid >> 6, lane = tid & 63;
    const int sr  = tid >> 2;
    const int skc = (tid & 3) * 8;

    const short* aSrc = h + (size_t)(row0 + sr) * I_DIM;
    const float* bSrc = W + (size_t)(col0 + sr) * I_DIM;

    const int frow = lane & 15, fk = (lane >> 4) * 8;

    f32x4 acc[4];
#pragma unroll
    for (int n = 0; n < 4; n++) acc[n] = (f32x4){0.f, 0.f, 0.f, 0.f};

    for (int k0 = 0; k0 < I_DIM; k0 += BK) {
        const short8 av = *(const short8*)(aSrc + k0 + skc);
        const float4 g0 = *(const float4*)(bSrc + k0 + skc);
        const float4 g1 = *(const float4*)(bSrc + k0 + skc + 4);
        const short8 bv = (short8){ f2bf(g0.x), f2bf(g0.y), f2bf(g0.z), f2bf(g0.w),
                                    f2bf(g1.x), f2bf(g1.y), f2bf(g1.z), f2bf(g1.w) };
        *(short8*)(&As[sr*LDSW + skc]) = av;
        *(short8*)(&Bs[sr*LDSW + skc]) = bv;
        __syncthreads();

        const short8 af = *(short8*)(&As[(wid*16 + frow)*LDSW + fk]);
#pragma unroll
        for (int n = 0; n < 4; n++) {
            const short8 bf = *(short8*)(&Bs[(n*16 + frow)*LDSW + fk]);
            acc[n] = __builtin_amdgcn_mfma_f32_16x16x32_bf16(af, bf, acc[n], 0, 0, 0);
        }
        __syncthreads();
    }

    const int srow0 = row0 + wid*16 + (lane >> 4) * 4;
    const int ocol0 = col0 + (lane & 15);
#pragma unroll
    for (int r = 0; r < 4; r++) {
        const int slot = srow0 + r;
        const int tok = tok_of_slot[slot];
        if (tok < 0) continue;
        const float w = w_of_slot[slot];
#pragma unroll
        for (int n = 0; n < 4; n++) {
            atomicAdd(&y[(size_t)tok * H_DIM + ocol0 + n*16], w * acc[n][r]);
        }
    }
}

// ---------------- launch ----------------
extern "C" void kernel_launch(void* const* d_in, const int* in_sizes, int n_in,
                              void* d_out, int out_size, void* d_ws, size_t ws_size,
                              hipStream_t stream) {
    const float* x  = (const float*)d_in[0];
    const float* Wg = (const float*)d_in[1];
    const float* W1 = (const float*)d_in[2];
    const float* W2 = (const float*)d_in[3];
    float* y = (float*)d_out;

    char* ws = (char*)d_ws;
    int*   cnt         = (int*)  (ws + 0);
    int*   fill        = (int*)  (ws + 64);
    int*   aoff        = (int*)  (ws + 128);
    int*   tokE        = (int*)  (ws + 256);
    float* tokW        = (float*)(ws + 256 + NTOK*2*4);
    int*   tok_of_slot = (int*)  (ws + 256 + NTOK*4*4);
    float* w_of_slot   = (float*)(ws + 256 + NTOK*4*4 + MAXS*4);
    short* h           = (short*)(ws + 139520);   // 256 + 64KB + 72KB, 256B-aligned

    hipMemsetAsync(ws, 0, 256, stream);                       // cnt, fill, aoff
    hipMemsetAsync(tok_of_slot, 0xFF, MAXS*4, stream);        // all -1
    hipMemsetAsync(y, 0, (size_t)out_size * 4, stream);

    gate_kernel<<<NTOK/4, 256, 0, stream>>>(x, Wg, cnt, tokE, tokW);
    scan_kernel<<<1, 64, 0, stream>>>(cnt, aoff);
    scatter_kernel<<<NTOK/256, 256, 0, stream>>>(tokE, tokW, aoff, fill, tok_of_slot, w_of_slot);
    fc1_kernel<<<dim3(I_DIM/BN, MAXRB), 256, 0, stream>>>(x, W1, aoff, tok_of_slot, h);
    fc2_kernel<<<dim3(H_DIM/BN, MAXRB), 256, 0, stream>>>(h, W2, aoff, tok_of_slot, w_of_slot, y);
}

// Round 2
// 366.271 us; speedup vs baseline: 1.1873x; 1.1873x over previous
//
#include <hip/hip_runtime.h>
#include <hip/hip_bf16.h>

#define H_DIM 1024
#define I_DIM 2048
#define NEXP  16
#define NTOK  4096
#define BM 128
#define BN 128
#define BK 32
#define MAXS 10240                   // 8192 + 16*127 padding, rounded
#define MAXRB (MAXS/BM)              // 80 row blocks

typedef __attribute__((ext_vector_type(8))) short short8;
typedef __attribute__((ext_vector_type(4))) float f32x4;

// ws layout (bytes)
#define OFF_TOKE 256
#define OFF_TOKW 33024
#define OFF_TOS  65792
#define OFF_WOS  106752
#define OFF_H    147712
#define OFF_XBF  42090752ULL
#define OFF_WBF  50479360ULL
#define NEED_FULL 117588224ULL

#define GLDS16(gsrc, ldst) \
  __builtin_amdgcn_global_load_lds((const __attribute__((address_space(1))) void*)(gsrc), \
                                   (__attribute__((address_space(3))) void*)(ldst), 16, 0, 0)

__device__ inline short f2bf(float f) {
    union { float f; unsigned u; } v; v.f = f;
    unsigned u = v.u + 0x7FFFu + ((v.u >> 16) & 1u);   // RNE
    return (short)(u >> 16);
}

__device__ inline short8 pack8(const float4 a, const float4 b) {
    return (short8){ f2bf(a.x), f2bf(a.y), f2bf(a.z), f2bf(a.w),
                     f2bf(b.x), f2bf(b.y), f2bf(b.z), f2bf(b.w) };
}

// ---------------- fp32 -> bf16 streaming convert ----------------
__global__ __launch_bounds__(256) void conv_kernel(
    const float* __restrict__ src, short* __restrict__ dst, int n8)
{
    int i = blockIdx.x * blockDim.x + threadIdx.x;
    const int stride = gridDim.x * blockDim.x;
    for (; i < n8; i += stride) {
        const float4 f0 = ((const float4*)src)[2*i];
        const float4 f1 = ((const float4*)src)[2*i+1];
        ((short8*)dst)[i] = pack8(f0, f1);
    }
}

// ---------------- gate: one wave per token ----------------
__global__ __launch_bounds__(256) void gate_kernel(
    const float* __restrict__ x, const float* __restrict__ Wg,
    int* __restrict__ cnt, int* __restrict__ tokE, float* __restrict__ tokW)
{
    const int wave = (blockIdx.x * blockDim.x + threadIdx.x) >> 6;   // token id
    const int lane = threadIdx.x & 63;
    if (wave >= NTOK) return;
    const float* xr = x + (size_t)wave * H_DIM;

    float acc[NEXP];
#pragma unroll
    for (int e = 0; e < NEXP; e++) acc[e] = 0.f;
    for (int j = lane; j < H_DIM; j += 64) {
        const float xv = xr[j];
#pragma unroll
        for (int e = 0; e < NEXP; e++) acc[e] = fmaf(xv, Wg[e * H_DIM + j], acc[e]);
    }
#pragma unroll
    for (int off = 32; off; off >>= 1) {
#pragma unroll
        for (int e = 0; e < NEXP; e++) acc[e] += __shfl_xor(acc[e], off, 64);
    }
    if (lane == 0) {
        float m = acc[0];
#pragma unroll
        for (int e = 1; e < NEXP; e++) m = fmaxf(m, acc[e]);
        float p[NEXP]; float s = 0.f;
#pragma unroll
        for (int e = 0; e < NEXP; e++) { p[e] = __expf(acc[e] - m); s += p[e]; }
        int i1 = 0;
#pragma unroll
        for (int e = 1; e < NEXP; e++) if (acc[e] > acc[i1]) i1 = e;
        int i2 = -1;
#pragma unroll
        for (int e = 0; e < NEXP; e++) {
            if (e == i1) continue;
            if (i2 < 0 || acc[e] > acc[i2]) i2 = e;
        }
        const float inv = 1.f / s;
        tokE[wave*2+0] = i1; tokW[wave*2+0] = p[i1] * inv;
        tokE[wave*2+1] = i2; tokW[wave*2+1] = p[i2] * inv;
        atomicAdd(&cnt[i1], 1); atomicAdd(&cnt[i2], 1);
    }
}

// ---------------- scan: BM-aligned prefix sum ----------------
__global__ void scan_kernel(const int* __restrict__ cnt, int* __restrict__ aoff)
{
    if (threadIdx.x == 0 && blockIdx.x == 0) {
        int acc = 0;
        for (int e = 0; e < NEXP; e++) {
            aoff[e] = acc;
            acc += ((cnt[e] + BM - 1) / BM) * BM;
        }
        aoff[NEXP] = acc;
    }
}

// ---------------- scatter: fill compacted slot lists ----------------
__global__ __launch_bounds__(256) void scatter_kernel(
    const int* __restrict__ tokE, const float* __restrict__ tokW,
    const int* __restrict__ aoff, int* __restrict__ fill,
    int* __restrict__ tok_of_slot, float* __restrict__ w_of_slot)
{
    const int t = blockIdx.x * blockDim.x + threadIdx.x;
    if (t >= NTOK) return;
#pragma unroll
    for (int k = 0; k < 2; k++) {
        const int e = tokE[t*2+k];
        const int pos = atomicAdd(&fill[e], 1);
        const int slot = aoff[e] + pos;
        tok_of_slot[slot] = t;
        w_of_slot[slot] = tokW[t*2+k];
    }
}

// ---------------- fc1: h = silu(X W1^T), 128x128 tile ----------------
// MODE 0: xsrc/w1src are bf16 (pre-converted), global_load_lds staging.
// MODE 1: xsrc/w1src are fp32, reg-convert staging.
template<int MODE>
__global__ __launch_bounds__(256) void fc1_kernel_t(
    const void* __restrict__ xsrc, const void* __restrict__ w1src,
    const int* __restrict__ aoff, const int* __restrict__ tok_of_slot,
    short* __restrict__ h)
{
    const int total = aoff[NEXP];
    const int row0 = blockIdx.y * BM;
    if (row0 >= total) return;
    int e = 0;
    while (aoff[e+1] <= row0) e++;
    const int col0 = blockIdx.x * BN;

    __shared__ short As[BM*BK];   // [128][32] linear, row = 64B
    __shared__ short Bs[BN*BK];

    const int tid = threadIdx.x, wid = tid>>6, lane = tid&63;
    const int wr = wid>>1, wc = wid&1;

    const int srow = wid*32 + (lane>>2);       // staged row, chunk0 (chunk1 = +16)
    const int skc  = (lane&3)*8;               // staged k offset (elems)

    int t0 = tok_of_slot[row0 + srow];      if (t0 < 0) t0 = 0;
    int t1 = tok_of_slot[row0 + srow + 16]; if (t1 < 0) t1 = 0;

    const short *sa0=nullptr,*sa1=nullptr,*sb0=nullptr,*sb1=nullptr;
    const float *fa0=nullptr,*fa1=nullptr,*fb0=nullptr,*fb1=nullptr;
    if constexpr (MODE == 0) {
        const short* xb = (const short*)xsrc;
        const short* wb = (const short*)w1src + (size_t)e * I_DIM * H_DIM;
        sa0 = xb + (size_t)t0 * H_DIM + skc;
        sa1 = xb + (size_t)t1 * H_DIM + skc;
        sb0 = wb + (size_t)(col0 + srow)      * H_DIM + skc;
        sb1 = wb + (size_t)(col0 + srow + 16) * H_DIM + skc;
    } else {
        const float* xf = (const float*)xsrc;
        const float* wf = (const float*)w1src + (size_t)e * I_DIM * H_DIM;
        fa0 = xf + (size_t)t0 * H_DIM + skc;
        fa1 = xf + (size_t)t1 * H_DIM + skc;
        fb0 = wf + (size_t)(col0 + srow)      * H_DIM + skc;
        fb1 = wf + (size_t)(col0 + srow + 16) * H_DIM + skc;
    }
    short* la0 = &As[(wid*2+0)*512];
    short* la1 = &As[(wid*2+1)*512];
    short* lb0 = &Bs[(wid*2+0)*512];
    short* lb1 = &Bs[(wid*2+1)*512];

    const int frow = lane & 15, fko = (lane>>4)*8;

    f32x4 acc[4][4];
#pragma unroll
    for (int m=0;m<4;m++)
#pragma unroll
        for (int n=0;n<4;n++) acc[m][n] = (f32x4){0.f,0.f,0.f,0.f};

    for (int k0 = 0; k0 < H_DIM; k0 += BK) {
        if constexpr (MODE == 0) {
            GLDS16(sa0 + k0, la0);
            GLDS16(sa1 + k0, la1);
            GLDS16(sb0 + k0, lb0);
            GLDS16(sb1 + k0, lb1);
        } else {
            const float4 a00 = *(const float4*)(fa0 + k0), a01 = *(const float4*)(fa0 + k0 + 4);
            const float4 a10 = *(const float4*)(fa1 + k0), a11 = *(const float4*)(fa1 + k0 + 4);
            const float4 b00 = *(const float4*)(fb0 + k0), b01 = *(const float4*)(fb0 + k0 + 4);
            const float4 b10 = *(const float4*)(fb1 + k0), b11 = *(const float4*)(fb1 + k0 + 4);
            *(short8*)&As[srow*32 + skc]      = pack8(a00, a01);
            *(short8*)&As[(srow+16)*32 + skc] = pack8(a10, a11);
            *(short8*)&Bs[srow*32 + skc]      = pack8(b00, b01);
            *(short8*)&Bs[(srow+16)*32 + skc] = pack8(b10, b11);
        }
        __syncthreads();

        short8 af[4], bfr[4];
#pragma unroll
        for (int m=0;m<4;m++) af[m]  = *(const short8*)&As[(wr*64 + m*16 + frow)*32 + fko];
#pragma unroll
        for (int n=0;n<4;n++) bfr[n] = *(const short8*)&Bs[(wc*64 + n*16 + frow)*32 + fko];
#pragma unroll
        for (int m=0;m<4;m++)
#pragma unroll
            for (int n=0;n<4;n++)
                acc[m][n] = __builtin_amdgcn_mfma_f32_16x16x32_bf16(af[m], bfr[n], acc[m][n], 0, 0, 0);
        __syncthreads();
    }

    // epilogue: SiLU -> bf16 h. D layout: col=lane&15, row=(lane>>4)*4+r
    const int mr0 = row0 + wr*64 + (lane>>4)*4;
    const int nc0 = col0 + wc*64 + (lane&15);
#pragma unroll
    for (int m=0;m<4;m++)
#pragma unroll
        for (int n=0;n<4;n++)
#pragma unroll
            for (int r=0;r<4;r++) {
                const float v = acc[m][n][r];
                const float sv = v / (1.f + __expf(-v));
                h[(size_t)(mr0 + m*16 + r) * I_DIM + nc0 + n*16] = f2bf(sv);
            }
}

// ---------------- fc2: y[tok] += w * (h W2^T), 128x128 tile ----------------
// A (h) is always bf16 via global_load_lds. MODE selects W2 staging.
template<int MODE>
__global__ __launch_bounds__(256) void fc2_kernel_t(
    const short* __restrict__ h, const void* __restrict__ w2src,
    const int* __restrict__ aoff, const int* __restrict__ tok_of_slot,
    const float* __restrict__ w_of_slot, float* __restrict__ y)
{
    const int total = aoff[NEXP];
    const int row0 = blockIdx.y * BM;
    if (row0 >= total) return;
    int e = 0;
    while (aoff[e+1] <= row0) e++;
    const int col0 = blockIdx.x * BN;

    __shared__ short As[BM*BK];
    __shared__ short Bs[BN*BK];

    const int tid = threadIdx.x, wid = tid>>6, lane = tid&63;
    const int wr = wid>>1, wc = wid&1;

    const int srow = wid*32 + (lane>>2);
    const int skc  = (lane&3)*8;

    const short* sa0 = h + (size_t)(row0 + srow)      * I_DIM + skc;
    const short* sa1 = h + (size_t)(row0 + srow + 16) * I_DIM + skc;

    const short *sb0=nullptr,*sb1=nullptr;
    const float *fb0=nullptr,*fb1=nullptr;
    if constexpr (MODE == 0) {
        const short* wb = (const short*)w2src + (size_t)e * H_DIM * I_DIM;
        sb0 = wb + (size_t)(col0 + srow)      * I_DIM + skc;
        sb1 = wb + (size_t)(col0 + srow + 16) * I_DIM + skc;
    } else {
        const float* wf = (const float*)w2src + (size_t)e * H_DIM * I_DIM;
        fb0 = wf + (size_t)(col0 + srow)      * I_DIM + skc;
        fb1 = wf + (size_t)(col0 + srow + 16) * I_DIM + skc;
    }
    short* la0 = &As[(wid*2+0)*512];
    short* la1 = &As[(wid*2+1)*512];
    short* lb0 = &Bs[(wid*2+0)*512];
    short* lb1 = &Bs[(wid*2+1)*512];

    const int frow = lane & 15, fko = (lane>>4)*8;

    f32x4 acc[4][4];
#pragma unroll
    for (int m=0;m<4;m++)
#pragma unroll
        for (int n=0;n<4;n++) acc[m][n] = (f32x4){0.f,0.f,0.f,0.f};

    for (int k0 = 0; k0 < I_DIM; k0 += BK) {
        GLDS16(sa0 + k0, la0);
        GLDS16(sa1 + k0, la1);
        if constexpr (MODE == 0) {
            GLDS16(sb0 + k0, lb0);
            GLDS16(sb1 + k0, lb1);
        } else {
            const float4 b00 = *(const float4*)(fb0 + k0), b01 = *(const float4*)(fb0 + k0 + 4);
            const float4 b10 = *(const float4*)(fb1 + k0), b11 = *(const float4*)(fb1 + k0 + 4);
            *(short8*)&Bs[srow*32 + skc]      = pack8(b00, b01);
            *(short8*)&Bs[(srow+16)*32 + skc] = pack8(b10, b11);
        }
        __syncthreads();

        short8 af[4], bfr[4];
#pragma unroll
        for (int m=0;m<4;m++) af[m]  = *(const short8*)&As[(wr*64 + m*16 + frow)*32 + fko];
#pragma unroll
        for (int n=0;n<4;n++) bfr[n] = *(const short8*)&Bs[(wc*64 + n*16 + frow)*32 + fko];
#pragma unroll
        for (int m=0;m<4;m++)
#pragma unroll
            for (int n=0;n<4;n++)
                acc[m][n] = __builtin_amdgcn_mfma_f32_16x16x32_bf16(af[m], bfr[n], acc[m][n], 0, 0, 0);
        __syncthreads();
    }

    const int mr0 = row0 + wr*64 + (lane>>4)*4;
    const int nc0 = col0 + wc*64 + (lane&15);
#pragma unroll
    for (int m=0;m<4;m++)
#pragma unroll
        for (int r=0;r<4;r++) {
            const int slot = mr0 + m*16 + r;
            const int tok = tok_of_slot[slot];
            if (tok < 0) continue;
            const float w = w_of_slot[slot];
#pragma unroll
            for (int n=0;n<4;n++)
                atomicAdd(&y[(size_t)tok * H_DIM + nc0 + n*16], w * acc[m][n][r]);
        }
}

// ---------------- launch ----------------
extern "C" void kernel_launch(void* const* d_in, const int* in_sizes, int n_in,
                              void* d_out, int out_size, void* d_ws, size_t ws_size,
                              hipStream_t stream) {
    const float* x  = (const float*)d_in[0];
    const float* Wg = (const float*)d_in[1];
    const float* W1 = (const float*)d_in[2];
    const float* W2 = (const float*)d_in[3];
    float* y = (float*)d_out;

    char* ws = (char*)d_ws;
    int*   cnt         = (int*)  (ws + 0);
    int*   fill        = (int*)  (ws + 64);
    int*   aoff        = (int*)  (ws + 128);
    int*   tokE        = (int*)  (ws + OFF_TOKE);
    float* tokW        = (float*)(ws + OFF_TOKW);
    int*   tok_of_slot = (int*)  (ws + OFF_TOS);
    float* w_of_slot   = (float*)(ws + OFF_WOS);
    short* h           = (short*)(ws + OFF_H);
    short* xbf         = (short*)(ws + OFF_XBF);
    short* wbf         = (short*)(ws + OFF_WBF);

    const bool full = (ws_size >= NEED_FULL);

    hipMemsetAsync(ws, 0, 256, stream);                       // cnt, fill, aoff
    hipMemsetAsync(tok_of_slot, 0xFF, MAXS*4, stream);        // all -1
    hipMemsetAsync(y, 0, (size_t)out_size * 4, stream);

    gate_kernel<<<NTOK/4, 256, 0, stream>>>(x, Wg, cnt, tokE, tokW);
    scan_kernel<<<1, 64, 0, stream>>>(cnt, aoff);
    scatter_kernel<<<NTOK/256, 256, 0, stream>>>(tokE, tokW, aoff, fill, tok_of_slot, w_of_slot);

    if (full) {
        conv_kernel<<<2048, 256, 0, stream>>>(W1, wbf, NEXP*I_DIM*H_DIM/8);
        conv_kernel<<<2048, 256, 0, stream>>>(x, xbf, NTOK*H_DIM/8);
        fc1_kernel_t<0><<<dim3(I_DIM/BN, MAXRB), 256, 0, stream>>>(xbf, wbf, aoff, tok_of_slot, h);
        conv_kernel<<<2048, 256, 0, stream>>>(W2, wbf, NEXP*H_DIM*I_DIM/8);
        fc2_kernel_t<0><<<dim3(H_DIM/BN, MAXRB), 256, 0, stream>>>(h, wbf, aoff, tok_of_slot, w_of_slot, y);
    } else {
        fc1_kernel_t<1><<<dim3(I_DIM/BN, MAXRB), 256, 0, stream>>>(x, W1, aoff, tok_of_slot, h);
        fc2_kernel_t<1><<<dim3(H_DIM/BN, MAXRB), 256, 0, stream>>>(h, W2, aoff, tok_of_slot, w_of_slot, y);
    }
}

// Round 3
// 265.456 us; speedup vs baseline: 1.6382x; 1.3798x over previous
//
#include <hip/hip_runtime.h>
#include <hip/hip_bf16.h>

#define H_DIM 1024
#define I_DIM 2048
#define NEXP  16
#define NTOK  4096
#define BM 128
#define BN 128
#define BK 32
#define MAXS 10240                   // 8192 + 16*127 padding, rounded
#define MAXRB (MAXS/BM)              // 80 row blocks
#define PAIRS (NTOK*2)
#define SORT_T 256
#define PPT (PAIRS/SORT_T)           // 32 pairs per thread

typedef __attribute__((ext_vector_type(8))) short short8;
typedef __attribute__((ext_vector_type(4))) float f32x4;

// ws layout (bytes)
#define OFF_TOKE 256
#define OFF_TOKW 33024
#define OFF_TOS  65792
#define OFF_WOS  106752
#define OFF_H    147712
#define OFF_XBF  42090752ULL
#define OFF_WBF  50479360ULL
#define NEED_FULL 117588224ULL

#define GLDS16(gsrc, ldst) \
  __builtin_amdgcn_global_load_lds((const __attribute__((address_space(1))) void*)(gsrc), \
                                   (__attribute__((address_space(3))) void*)(ldst), 16, 0, 0)

__device__ inline short f2bf(float f) {
    union { float f; unsigned u; } v; v.f = f;
    unsigned u = v.u + 0x7FFFu + ((v.u >> 16) & 1u);   // RNE
    return (short)(u >> 16);
}

__device__ inline short8 pack8(const float4 a, const float4 b) {
    return (short8){ f2bf(a.x), f2bf(a.y), f2bf(a.z), f2bf(a.w),
                     f2bf(b.x), f2bf(b.y), f2bf(b.z), f2bf(b.w) };
}

// ---------------- fp32 -> bf16 streaming convert ----------------
__global__ __launch_bounds__(256) void conv_kernel(
    const float* __restrict__ src, short* __restrict__ dst, int n8)
{
    int i = blockIdx.x * blockDim.x + threadIdx.x;
    const int stride = gridDim.x * blockDim.x;
    for (; i < n8; i += stride) {
        const float4 f0 = ((const float4*)src)[2*i];
        const float4 f1 = ((const float4*)src)[2*i+1];
        ((short8*)dst)[i] = pack8(f0, f1);
    }
}

// ---------------- gate: one wave per token, NO atomics ----------------
__global__ __launch_bounds__(256) void gate_kernel(
    const float* __restrict__ x, const float* __restrict__ Wg,
    int* __restrict__ tokE, float* __restrict__ tokW)
{
    const int wave = (blockIdx.x * blockDim.x + threadIdx.x) >> 6;   // token id
    const int lane = threadIdx.x & 63;
    if (wave >= NTOK) return;
    const float* xr = x + (size_t)wave * H_DIM;

    float acc[NEXP];
#pragma unroll
    for (int e = 0; e < NEXP; e++) acc[e] = 0.f;
    for (int j = lane; j < H_DIM; j += 64) {
        const float xv = xr[j];
#pragma unroll
        for (int e = 0; e < NEXP; e++) acc[e] = fmaf(xv, Wg[e * H_DIM + j], acc[e]);
    }
#pragma unroll
    for (int off = 32; off; off >>= 1) {
#pragma unroll
        for (int e = 0; e < NEXP; e++) acc[e] += __shfl_xor(acc[e], off, 64);
    }
    if (lane == 0) {
        float m = acc[0];
#pragma unroll
        for (int e = 1; e < NEXP; e++) m = fmaxf(m, acc[e]);
        float p[NEXP]; float s = 0.f;
#pragma unroll
        for (int e = 0; e < NEXP; e++) { p[e] = __expf(acc[e] - m); s += p[e]; }
        int i1 = 0;
#pragma unroll
        for (int e = 1; e < NEXP; e++) if (acc[e] > acc[i1]) i1 = e;
        int i2 = -1;
#pragma unroll
        for (int e = 0; e < NEXP; e++) {
            if (e == i1) continue;
            if (i2 < 0 || acc[e] > acc[i2]) i2 = e;
        }
        const float inv = 1.f / s;
        tokE[wave*2+0] = i1; tokW[wave*2+0] = p[i1] * inv;
        tokE[wave*2+1] = i2; tokW[wave*2+1] = p[i2] * inv;
    }
}

// ---------------- sort: single-block counting sort, no atomics ----------------
// Builds aoff (BM-aligned per-expert offsets) and compacted slot lists.
__global__ __launch_bounds__(SORT_T) void sort_kernel(
    const int* __restrict__ tokE, const float* __restrict__ tokW,
    int* __restrict__ aoff, int* __restrict__ tok_of_slot, float* __restrict__ w_of_slot)
{
    __shared__ int hist[NEXP * SORT_T];   // [e][t]
    __shared__ int tot[NEXP];
    __shared__ int aoff_l[NEXP + 1];

    const int tid = threadIdx.x;
    const int lane = tid & 63, wv = tid >> 6;

    // cache this thread's expert ids in registers (unrolled -> static idx)
    int eloc[PPT];
#pragma unroll
    for (int i = 0; i < PPT; i++) eloc[i] = tokE[tid * PPT + i];

    // per-thread histogram kept in LDS column tid (no runtime-indexed reg array)
#pragma unroll
    for (int e = 0; e < NEXP; e++) hist[e * SORT_T + tid] = 0;
    __syncthreads();
#pragma unroll
    for (int i = 0; i < PPT; i++) hist[eloc[i] * SORT_T + tid]++;
    __syncthreads();

    // exclusive scan over the 256 thread-counts, per expert (4 waves x 4 experts)
#pragma unroll
    for (int r = 0; r < 4; r++) {
        const int e = wv * 4 + r;
        const int base = e * SORT_T + lane * 4;
        int v0 = hist[base+0], v1 = hist[base+1], v2 = hist[base+2], v3 = hist[base+3];
        const int s = v0 + v1 + v2 + v3;
        int incl = s;
#pragma unroll
        for (int off = 1; off < 64; off <<= 1) {
            const int t = __shfl_up(incl, off, 64);
            if (lane >= off) incl += t;
        }
        int run = incl - s;          // exclusive prefix for this lane's 4 slots
        hist[base+0] = run; run += v0;
        hist[base+1] = run; run += v1;
        hist[base+2] = run; run += v2;
        hist[base+3] = run;
        if (lane == 63) tot[e] = incl;
    }
    __syncthreads();

    if (tid == 0) {
        int acc = 0;
#pragma unroll
        for (int e = 0; e < NEXP; e++) {
            aoff_l[e] = acc; aoff[e] = acc;
            acc += ((tot[e] + BM - 1) / BM) * BM;
        }
        aoff_l[NEXP] = acc; aoff[NEXP] = acc;
    }
    __syncthreads();

    // deterministic slot assignment: hist[e][tid] is this thread's running cursor
#pragma unroll
    for (int i = 0; i < PPT; i++) {
        const int p = tid * PPT + i;
        const int e = eloc[i];
        const int idx = hist[e * SORT_T + tid]++;
        const int slot = aoff_l[e] + idx;
        tok_of_slot[slot] = p >> 1;
        w_of_slot[slot] = tokW[p];
    }
}

// ---------------- fc1: h = silu(X W1^T), 128x128 tile ----------------
template<int MODE>
__global__ __launch_bounds__(256) void fc1_kernel_t(
    const void* __restrict__ xsrc, const void* __restrict__ w1src,
    const int* __restrict__ aoff, const int* __restrict__ tok_of_slot,
    short* __restrict__ h)
{
    const int total = aoff[NEXP];
    const int row0 = blockIdx.y * BM;
    if (row0 >= total) return;
    int e = 0;
    while (aoff[e+1] <= row0) e++;
    const int col0 = blockIdx.x * BN;

    __shared__ short As[BM*BK];   // [128][32] linear
    __shared__ short Bs[BN*BK];

    const int tid = threadIdx.x, wid = tid>>6, lane = tid&63;
    const int wr = wid>>1, wc = wid&1;

    const int srow = wid*32 + (lane>>2);       // staged row, chunk0 (chunk1 = +16)
    const int skc  = (lane&3)*8;               // staged k offset (elems)

    int t0 = tok_of_slot[row0 + srow];      if (t0 < 0) t0 = 0;
    int t1 = tok_of_slot[row0 + srow + 16]; if (t1 < 0) t1 = 0;

    const short *sa0=nullptr,*sa1=nullptr,*sb0=nullptr,*sb1=nullptr;
    const float *fa0=nullptr,*fa1=nullptr,*fb0=nullptr,*fb1=nullptr;
    if constexpr (MODE == 0) {
        const short* xb = (const short*)xsrc;
        const short* wb = (const short*)w1src + (size_t)e * I_DIM * H_DIM;
        sa0 = xb + (size_t)t0 * H_DIM + skc;
        sa1 = xb + (size_t)t1 * H_DIM + skc;
        sb0 = wb + (size_t)(col0 + srow)      * H_DIM + skc;
        sb1 = wb + (size_t)(col0 + srow + 16) * H_DIM + skc;
    } else {
        const float* xf = (const float*)xsrc;
        const float* wf = (const float*)w1src + (size_t)e * I_DIM * H_DIM;
        fa0 = xf + (size_t)t0 * H_DIM + skc;
        fa1 = xf + (size_t)t1 * H_DIM + skc;
        fb0 = wf + (size_t)(col0 + srow)      * H_DIM + skc;
        fb1 = wf + (size_t)(col0 + srow + 16) * H_DIM + skc;
    }
    short* la0 = &As[(wid*2+0)*512];
    short* la1 = &As[(wid*2+1)*512];
    short* lb0 = &Bs[(wid*2+0)*512];
    short* lb1 = &Bs[(wid*2+1)*512];

    const int frow = lane & 15, fko = (lane>>4)*8;

    f32x4 acc[4][4];
#pragma unroll
    for (int m=0;m<4;m++)
#pragma unroll
        for (int n=0;n<4;n++) acc[m][n] = (f32x4){0.f,0.f,0.f,0.f};

    for (int k0 = 0; k0 < H_DIM; k0 += BK) {
        if constexpr (MODE == 0) {
            GLDS16(sa0 + k0, la0);
            GLDS16(sa1 + k0, la1);
            GLDS16(sb0 + k0, lb0);
            GLDS16(sb1 + k0, lb1);
        } else {
            const float4 a00 = *(const float4*)(fa0 + k0), a01 = *(const float4*)(fa0 + k0 + 4);
            const float4 a10 = *(const float4*)(fa1 + k0), a11 = *(const float4*)(fa1 + k0 + 4);
            const float4 b00 = *(const float4*)(fb0 + k0), b01 = *(const float4*)(fb0 + k0 + 4);
            const float4 b10 = *(const float4*)(fb1 + k0), b11 = *(const float4*)(fb1 + k0 + 4);
            *(short8*)&As[srow*32 + skc]      = pack8(a00, a01);
            *(short8*)&As[(srow+16)*32 + skc] = pack8(a10, a11);
            *(short8*)&Bs[srow*32 + skc]      = pack8(b00, b01);
            *(short8*)&Bs[(srow+16)*32 + skc] = pack8(b10, b11);
        }
        __syncthreads();

        short8 af[4], bfr[4];
#pragma unroll
        for (int m=0;m<4;m++) af[m]  = *(const short8*)&As[(wr*64 + m*16 + frow)*32 + fko];
#pragma unroll
        for (int n=0;n<4;n++) bfr[n] = *(const short8*)&Bs[(wc*64 + n*16 + frow)*32 + fko];
#pragma unroll
        for (int m=0;m<4;m++)
#pragma unroll
            for (int n=0;n<4;n++)
                acc[m][n] = __builtin_amdgcn_mfma_f32_16x16x32_bf16(af[m], bfr[n], acc[m][n], 0, 0, 0);
        __syncthreads();
    }

    // epilogue: SiLU -> bf16 h. D layout: col=lane&15, row=(lane>>4)*4+r
    const int mr0 = row0 + wr*64 + (lane>>4)*4;
    const int nc0 = col0 + wc*64 + (lane&15);
#pragma unroll
    for (int m=0;m<4;m++)
#pragma unroll
        for (int n=0;n<4;n++)
#pragma unroll
            for (int r=0;r<4;r++) {
                const float v = acc[m][n][r];
                const float sv = v / (1.f + __expf(-v));
                h[(size_t)(mr0 + m*16 + r) * I_DIM + nc0 + n*16] = f2bf(sv);
            }
}

// ---------------- fc2: y[tok] += w * (h W2^T), 128x128 tile ----------------
template<int MODE>
__global__ __launch_bounds__(256) void fc2_kernel_t(
    const short* __restrict__ h, const void* __restrict__ w2src,
    const int* __restrict__ aoff, const int* __restrict__ tok_of_slot,
    const float* __restrict__ w_of_slot, float* __restrict__ y)
{
    const int total = aoff[NEXP];
    const int row0 = blockIdx.y * BM;
    if (row0 >= total) return;
    int e = 0;
    while (aoff[e+1] <= row0) e++;
    const int col0 = blockIdx.x * BN;

    __shared__ short As[BM*BK];
    __shared__ short Bs[BN*BK];

    const int tid = threadIdx.x, wid = tid>>6, lane = tid&63;
    const int wr = wid>>1, wc = wid&1;

    const int srow = wid*32 + (lane>>2);
    const int skc  = (lane&3)*8;

    const short* sa0 = h + (size_t)(row0 + srow)      * I_DIM + skc;
    const short* sa1 = h + (size_t)(row0 + srow + 16) * I_DIM + skc;

    const short *sb0=nullptr,*sb1=nullptr;
    const float *fb0=nullptr,*fb1=nullptr;
    if constexpr (MODE == 0) {
        const short* wb = (const short*)w2src + (size_t)e * H_DIM * I_DIM;
        sb0 = wb + (size_t)(col0 + srow)      * I_DIM + skc;
        sb1 = wb + (size_t)(col0 + srow + 16) * I_DIM + skc;
    } else {
        const float* wf = (const float*)w2src + (size_t)e * H_DIM * I_DIM;
        fb0 = wf + (size_t)(col0 + srow)      * I_DIM + skc;
        fb1 = wf + (size_t)(col0 + srow + 16) * I_DIM + skc;
    }
    short* la0 = &As[(wid*2+0)*512];
    short* la1 = &As[(wid*2+1)*512];
    short* lb0 = &Bs[(wid*2+0)*512];
    short* lb1 = &Bs[(wid*2+1)*512];

    const int frow = lane & 15, fko = (lane>>4)*8;

    f32x4 acc[4][4];
#pragma unroll
    for (int m=0;m<4;m++)
#pragma unroll
        for (int n=0;n<4;n++) acc[m][n] = (f32x4){0.f,0.f,0.f,0.f};

    for (int k0 = 0; k0 < I_DIM; k0 += BK) {
        GLDS16(sa0 + k0, la0);
        GLDS16(sa1 + k0, la1);
        if constexpr (MODE == 0) {
            GLDS16(sb0 + k0, lb0);
            GLDS16(sb1 + k0, lb1);
        } else {
            const float4 b00 = *(const float4*)(fb0 + k0), b01 = *(const float4*)(fb0 + k0 + 4);
            const float4 b10 = *(const float4*)(fb1 + k0), b11 = *(const float4*)(fb1 + k0 + 4);
            *(short8*)&Bs[srow*32 + skc]      = pack8(b00, b01);
            *(short8*)&Bs[(srow+16)*32 + skc] = pack8(b10, b11);
        }
        __syncthreads();

        short8 af[4], bfr[4];
#pragma unroll
        for (int m=0;m<4;m++) af[m]  = *(const short8*)&As[(wr*64 + m*16 + frow)*32 + fko];
#pragma unroll
        for (int n=0;n<4;n++) bfr[n] = *(const short8*)&Bs[(wc*64 + n*16 + frow)*32 + fko];
#pragma unroll
        for (int m=0;m<4;m++)
#pragma unroll
            for (int n=0;n<4;n++)
                acc[m][n] = __builtin_amdgcn_mfma_f32_16x16x32_bf16(af[m], bfr[n], acc[m][n], 0, 0, 0);
        __syncthreads();
    }

    const int mr0 = row0 + wr*64 + (lane>>4)*4;
    const int nc0 = col0 + wc*64 + (lane&15);
#pragma unroll
    for (int m=0;m<4;m++)
#pragma unroll
        for (int r=0;r<4;r++) {
            const int slot = mr0 + m*16 + r;
            const int tok = tok_of_slot[slot];
            if (tok < 0) continue;
            const float w = w_of_slot[slot];
#pragma unroll
            for (int n=0;n<4;n++)
                atomicAdd(&y[(size_t)tok * H_DIM + nc0 + n*16], w * acc[m][n][r]);
        }
}

// ---------------- launch ----------------
extern "C" void kernel_launch(void* const* d_in, const int* in_sizes, int n_in,
                              void* d_out, int out_size, void* d_ws, size_t ws_size,
                              hipStream_t stream) {
    const float* x  = (const float*)d_in[0];
    const float* Wg = (const float*)d_in[1];
    const float* W1 = (const float*)d_in[2];
    const float* W2 = (const float*)d_in[3];
    float* y = (float*)d_out;

    char* ws = (char*)d_ws;
    int*   aoff        = (int*)  (ws + 128);
    int*   tokE        = (int*)  (ws + OFF_TOKE);
    float* tokW        = (float*)(ws + OFF_TOKW);
    int*   tok_of_slot = (int*)  (ws + OFF_TOS);
    float* w_of_slot   = (float*)(ws + OFF_WOS);
    short* h           = (short*)(ws + OFF_H);
    short* xbf         = (short*)(ws + OFF_XBF);
    short* wbf         = (short*)(ws + OFF_WBF);

    const bool full = (ws_size >= NEED_FULL);

    hipMemsetAsync(tok_of_slot, 0xFF, MAXS*4, stream);        // all -1
    hipMemsetAsync(y, 0, (size_t)out_size * 4, stream);

    gate_kernel<<<NTOK/4, 256, 0, stream>>>(x, Wg, tokE, tokW);
    sort_kernel<<<1, SORT_T, 0, stream>>>(tokE, tokW, aoff, tok_of_slot, w_of_slot);

    if (full) {
        conv_kernel<<<2048, 256, 0, stream>>>(W1, wbf, NEXP*I_DIM*H_DIM/8);
        conv_kernel<<<2048, 256, 0, stream>>>(x, xbf, NTOK*H_DIM/8);
        fc1_kernel_t<0><<<dim3(I_DIM/BN, MAXRB), 256, 0, stream>>>(xbf, wbf, aoff, tok_of_slot, h);
        conv_kernel<<<2048, 256, 0, stream>>>(W2, wbf, NEXP*H_DIM*I_DIM/8);
        fc2_kernel_t<0><<<dim3(H_DIM/BN, MAXRB), 256, 0, stream>>>(h, wbf, aoff, tok_of_slot, w_of_slot, y);
    } else {
        fc1_kernel_t<1><<<dim3(I_DIM/BN, MAXRB), 256, 0, stream>>>(x, W1, aoff, tok_of_slot, h);
        fc2_kernel_t<1><<<dim3(H_DIM/BN, MAXRB), 256, 0, stream>>>(h, W2, aoff, tok_of_slot, w_of_slot, y);
    }
}